// Round 1
// baseline (339.564 us; speedup 1.0000x reference)
//
#include <hip/hip_runtime.h>
#include <hip/hip_bf16.h>

#define N_ROWS 8192
#define DIM 256
#define TAU_INV 2.0f
#define BM 128
#define BK 64

typedef float f32x4 __attribute__((ext_vector_type(4)));
typedef short bf16x8 __attribute__((ext_vector_type(8)));

// ---------------------------------------------------------------------------
// Kernel 1: L2-normalize rows of z1,z2 -> bf16 An,Bn; also compute (in fp32,
// from the *quantized* bf16 values so they match what the MFMA diagonal sees):
//   d_aa[i] = sum(an_i^2), d_bb[i] = sum(bn_i^2), pos[i] = sum(an_i*bn_i)
// ---------------------------------------------------------------------------
__global__ __launch_bounds__(256) void normalize_kernel(
    const float* __restrict__ z1, const float* __restrict__ z2,
    __hip_bfloat16* __restrict__ An, __hip_bfloat16* __restrict__ Bn,
    float* __restrict__ d_aa, float* __restrict__ d_bb, float* __restrict__ pos)
{
    const int row = blockIdx.x;
    const int t = threadIdx.x;            // 0..255 == DIM
    const float a = z1[row * DIM + t];
    const float b = z2[row * DIM + t];

    __shared__ float red[4];

    auto blockSum = [&](float v) -> float {
        #pragma unroll
        for (int m = 1; m < 64; m <<= 1) v += __shfl_xor(v, m, 64);
        if ((t & 63) == 0) red[t >> 6] = v;
        __syncthreads();
        float r = red[0] + red[1] + red[2] + red[3];
        __syncthreads();
        return r;
    };

    const float na2 = blockSum(a * a);
    const float nb2 = blockSum(b * b);
    const float inv_a = 1.0f / sqrtf(na2);   // norms ~16; eps never binds
    const float inv_b = 1.0f / sqrtf(nb2);

    const __hip_bfloat16 ah = __float2bfloat16(a * inv_a);
    const __hip_bfloat16 bh = __float2bfloat16(b * inv_b);
    An[row * DIM + t] = ah;
    Bn[row * DIM + t] = bh;

    const float af = __bfloat162float(ah);
    const float bf = __bfloat162float(bh);
    const float qa = blockSum(af * af);
    const float qb = blockSum(bf * bf);
    const float qd = blockSum(af * bf);
    if (t == 0) { d_aa[row] = qa; d_bb[row] = qb; pos[row] = qd; }
}

// ---------------------------------------------------------------------------
// Kernel 2: fused Gram GEMM: C = X * Y^T (both [N,256] bf16 row-major),
// epilogue e = exp(C * 2), row sums -> atomicAdd Srow, col sums -> Scol
// (or, for symmetric upper-triangular tiles, col sums also feed Srow).
// m97 structure: 128x128 tile, BK=64, 4 waves, 4x4 frags of 16x16x32 bf16,
// global_load_lds width=16 staging.
// ---------------------------------------------------------------------------
__global__ __launch_bounds__(256) void gram_kernel(
    const __hip_bfloat16* __restrict__ X, const __hip_bfloat16* __restrict__ Y,
    float* __restrict__ Srow, float* __restrict__ Scol, int symmetric)
{
    const int ti = blockIdx.y;    // row tile
    const int tj = blockIdx.x;    // col tile
    if (symmetric && tj < ti) return;   // upper triangle only

    __shared__ __hip_bfloat16 As[BM * BK];   // 16 KB, row-major [128][64]
    __shared__ __hip_bfloat16 Bs[BM * BK];   // 16 KB

    const int tid  = threadIdx.x;
    const int wave = tid >> 6;
    const int lane = tid & 63;
    const int wr = wave >> 1;     // wave row (0..1) -> 64 rows
    const int wc = wave & 1;      // wave col

    const int rowBase = ti * BM;
    const int colBase = tj * BM;

    const int lm = lane & 15;           // m/n within 16x16 fragment
    const int lk = (lane >> 4) * 8;     // k base within fragment (quad*8)

    // staging lane geometry: 16 chunks of 1KB (8 rows x 128B); wave handles 4
    const int srow = lane >> 3;         // 0..7 row within chunk
    const int skel = (lane & 7) * 8;    // k element offset within BK

    f32x4 acc[4][4] = {};

    for (int k0 = 0; k0 < DIM; k0 += BK) {
        #pragma unroll
        for (int c = 0; c < 4; ++c) {
            const int chunk = wave * 4 + c;          // 0..15 (wave-uniform)
            const int r = chunk * 8 + srow;          // 0..127
            const __hip_bfloat16* ga = X + (size_t)(rowBase + r) * DIM + k0 + skel;
            const __hip_bfloat16* gb = Y + (size_t)(colBase + r) * DIM + k0 + skel;
            __builtin_amdgcn_global_load_lds(
                (const __attribute__((address_space(1))) void*)ga,
                (__attribute__((address_space(3))) void*)(As + chunk * 512),
                16, 0, 0);
            __builtin_amdgcn_global_load_lds(
                (const __attribute__((address_space(1))) void*)gb,
                (__attribute__((address_space(3))) void*)(Bs + chunk * 512),
                16, 0, 0);
        }
        __syncthreads();   // compiler drains vmcnt before barrier

        #pragma unroll
        for (int kk = 0; kk < BK; kk += 32) {
            bf16x8 afr[4], bfr[4];
            #pragma unroll
            for (int f = 0; f < 4; ++f) {
                afr[f] = *(const bf16x8*)(As + (wr * 64 + f * 16 + lm) * BK + kk + lk);
                bfr[f] = *(const bf16x8*)(Bs + (wc * 64 + f * 16 + lm) * BK + kk + lk);
            }
            #pragma unroll
            for (int fr = 0; fr < 4; ++fr)
                #pragma unroll
                for (int fc = 0; fc < 4; ++fc)
                    acc[fr][fc] = __builtin_amdgcn_mfma_f32_16x16x32_bf16(
                        afr[fr], bfr[fc], acc[fr][fc], 0, 0, 0);
        }
        __syncthreads();   // before restaging LDS
    }

    // ---- epilogue: exp, then row/col sums ----
    // C/D layout (verified m89/m91): col = lane&15, row = (lane>>4)*4 + reg
    #pragma unroll
    for (int fr = 0; fr < 4; ++fr)
        #pragma unroll
        for (int fc = 0; fc < 4; ++fc)
            #pragma unroll
            for (int r = 0; r < 4; ++r)
                acc[fr][fc][r] = __expf(acc[fr][fc][r] * TAU_INV);

    // row sums: sum over 16 cols (lane&15) x 4 col-frags
    #pragma unroll
    for (int fr = 0; fr < 4; ++fr) {
        #pragma unroll
        for (int r = 0; r < 4; ++r) {
            float s = acc[fr][0][r] + acc[fr][1][r] + acc[fr][2][r] + acc[fr][3][r];
            s += __shfl_xor(s, 1, 64);
            s += __shfl_xor(s, 2, 64);
            s += __shfl_xor(s, 4, 64);
            s += __shfl_xor(s, 8, 64);
            if ((lane & 15) == 0) {
                const int row = rowBase + wr * 64 + fr * 16 + (lane >> 4) * 4 + r;
                atomicAdd(&Srow[row], s);
            }
        }
    }

    // col sums: needed for AB (Scol) and for symmetric off-diagonal tiles
    const bool do_col = (Scol != nullptr) || (symmetric && ti != tj);
    if (do_col) {
        float* colDst = (Scol != nullptr) ? Scol : Srow;
        #pragma unroll
        for (int fc = 0; fc < 4; ++fc) {
            float s = 0.0f;
            #pragma unroll
            for (int fr = 0; fr < 4; ++fr)
                #pragma unroll
                for (int r = 0; r < 4; ++r)
                    s += acc[fr][fc][r];
            s += __shfl_xor(s, 16, 64);
            s += __shfl_xor(s, 32, 64);
            if (lane < 16) {
                const int col = colBase + wc * 64 + fc * 16 + lm;
                atomicAdd(&colDst[col], s);
            }
        }
    }
}

// ---------------------------------------------------------------------------
// Kernel 3: per-row loss + mean reduction.
// l_i = 0.5*(log(den1)+log(den2)) - 2*pos_i
// den1 = S_aa + S_ab_row - exp(2*d_aa); den2 = S_bb + S_ab_col - exp(2*d_bb)
// ---------------------------------------------------------------------------
__global__ __launch_bounds__(256) void loss_kernel(
    const float* __restrict__ S_aa, const float* __restrict__ S_abr,
    const float* __restrict__ S_abc, const float* __restrict__ S_bb,
    const float* __restrict__ d_aa, const float* __restrict__ d_bb,
    const float* __restrict__ pos, float* __restrict__ out)
{
    const int i = blockIdx.x * 256 + threadIdx.x;
    const float den1 = S_aa[i] + S_abr[i] - expf(TAU_INV * d_aa[i]);
    const float den2 = S_bb[i] + S_abc[i] - expf(TAU_INV * d_bb[i]);
    float v = 0.5f * (logf(den1) + logf(den2)) - TAU_INV * pos[i];

    __shared__ float red[4];
    #pragma unroll
    for (int m = 1; m < 64; m <<= 1) v += __shfl_xor(v, m, 64);
    if ((threadIdx.x & 63) == 0) red[threadIdx.x >> 6] = v;
    __syncthreads();
    if (threadIdx.x == 0)
        atomicAdd(out, (red[0] + red[1] + red[2] + red[3]) * (1.0f / N_ROWS));
}

// ---------------------------------------------------------------------------
extern "C" void kernel_launch(void* const* d_in, const int* in_sizes, int n_in,
                              void* d_out, int out_size, void* d_ws, size_t ws_size,
                              hipStream_t stream)
{
    const float* z1 = (const float*)d_in[0];
    const float* z2 = (const float*)d_in[1];
    float* out = (float*)d_out;

    char* ws = (char*)d_ws;
    __hip_bfloat16* An = (__hip_bfloat16*)ws;                        // 4 MB
    __hip_bfloat16* Bn = (__hip_bfloat16*)(ws + 4194304);            // 4 MB
    float* S_aa  = (float*)(ws + 8388608);
    float* S_abr = S_aa  + N_ROWS;
    float* S_abc = S_abr + N_ROWS;
    float* S_bb  = S_abc + N_ROWS;
    float* d_aa  = S_bb  + N_ROWS;
    float* d_bb  = d_aa  + N_ROWS;
    float* pos   = d_bb  + N_ROWS;

    // zero the atomic accumulators (ws/out are poisoned 0xAA before each call)
    hipMemsetAsync(S_aa, 0, 4 * N_ROWS * sizeof(float), stream);
    hipMemsetAsync(out, 0, sizeof(float), stream);

    normalize_kernel<<<N_ROWS, 256, 0, stream>>>(z1, z2, An, Bn, d_aa, d_bb, pos);

    dim3 grid(N_ROWS / BM, N_ROWS / BM);   // 64 x 64 tiles
    gram_kernel<<<grid, 256, 0, stream>>>(An, An, S_aa, nullptr, 1);
    gram_kernel<<<grid, 256, 0, stream>>>(Bn, Bn, S_bb, nullptr, 1);
    gram_kernel<<<grid, 256, 0, stream>>>(An, Bn, S_abr, S_abc, 0);

    loss_kernel<<<N_ROWS / 256, 256, 0, stream>>>(S_aa, S_abr, S_abc, S_bb,
                                                  d_aa, d_bb, pos, out);
}

// Round 2
// 217.944 us; speedup vs baseline: 1.5580x; 1.5580x over previous
//
#include <hip/hip_runtime.h>
#include <hip/hip_bf16.h>

#define N_ROWS 8192
#define DIM 256
#define TAU_INV 2.0f
#define BM 128
#define BK 64

typedef float f32x4 __attribute__((ext_vector_type(4)));
typedef short bf16x8 __attribute__((ext_vector_type(8)));

// ---------------------------------------------------------------------------
// Kernel 1: L2-normalize rows of z1,z2 -> bf16 An,Bn; also compute (in fp32,
// from the *quantized* bf16 values so they match the MFMA diagonal):
//   d_aa[i] = sum(an_i^2), d_bb[i] = sum(bn_i^2), pos[i] = sum(an_i*bn_i)
// ---------------------------------------------------------------------------
__global__ __launch_bounds__(256) void normalize_kernel(
    const float* __restrict__ z1, const float* __restrict__ z2,
    __hip_bfloat16* __restrict__ An, __hip_bfloat16* __restrict__ Bn,
    float* __restrict__ d_aa, float* __restrict__ d_bb, float* __restrict__ pos)
{
    const int row = blockIdx.x;
    const int t = threadIdx.x;            // 0..255 == DIM
    const float a = z1[row * DIM + t];
    const float b = z2[row * DIM + t];

    __shared__ float red[4];

    auto blockSum = [&](float v) -> float {
        #pragma unroll
        for (int m = 1; m < 64; m <<= 1) v += __shfl_xor(v, m, 64);
        if ((t & 63) == 0) red[t >> 6] = v;
        __syncthreads();
        float r = red[0] + red[1] + red[2] + red[3];
        __syncthreads();
        return r;
    };

    const float na2 = blockSum(a * a);
    const float nb2 = blockSum(b * b);
    const float inv_a = 1.0f / sqrtf(na2);   // norms ~16; eps never binds
    const float inv_b = 1.0f / sqrtf(nb2);

    const __hip_bfloat16 ah = __float2bfloat16(a * inv_a);
    const __hip_bfloat16 bh = __float2bfloat16(b * inv_b);
    An[row * DIM + t] = ah;
    Bn[row * DIM + t] = bh;

    const float af = __bfloat162float(ah);
    const float bf = __bfloat162float(bh);
    const float qa = blockSum(af * af);
    const float qb = blockSum(bf * bf);
    const float qd = blockSum(af * bf);
    if (t == 0) { d_aa[row] = qa; d_bb[row] = qb; pos[row] = qd; }
}

// ---------------------------------------------------------------------------
// Kernel 2: all three Gram GEMMs in ONE launch (grid.z = 0:AB, 1:AA, 2:BB).
// C = X * Y^T, epilogue e = exp(2C); row sums -> Srow, col sums -> Scol
// (symmetric modes: upper-triangular tiles only; off-diag col sums -> Srow).
//
// LDS layout is XOR-swizzled: LDS[r][g] holds global k-group g^(r&7)
// (16B groups). This breaks the 128B row stride -> same-bank pattern that
// cost 1.26e7 conflict cycles in R1. global_load_lds forces LDS addr =
// base + lane*16, but the GLOBAL address is per-lane, so the staging lane
// simply fetches the swizzled source group.
// ---------------------------------------------------------------------------
__global__ __launch_bounds__(256) void gram3_kernel(
    const __hip_bfloat16* __restrict__ An, const __hip_bfloat16* __restrict__ Bn,
    float* __restrict__ S_aa, float* __restrict__ S_bb,
    float* __restrict__ S_abr, float* __restrict__ S_abc)
{
    const int ti = blockIdx.y;    // row tile
    const int tj = blockIdx.x;    // col tile
    const int mode = blockIdx.z;

    const __hip_bfloat16 *X, *Y;
    float *Srow, *Scol;
    int symmetric;
    if (mode == 0)      { X = An; Y = Bn; Srow = S_abr; Scol = S_abc; symmetric = 0; }
    else if (mode == 1) { X = An; Y = An; Srow = S_aa;  Scol = nullptr; symmetric = 1; }
    else                { X = Bn; Y = Bn; Srow = S_bb;  Scol = nullptr; symmetric = 1; }

    if (symmetric && tj < ti) return;   // upper triangle only

    __shared__ __hip_bfloat16 As[BM * BK];   // 16 KB
    __shared__ __hip_bfloat16 Bs[BM * BK];   // 16 KB

    const int tid  = threadIdx.x;
    const int wave = tid >> 6;
    const int lane = tid & 63;
    const int wr = wave >> 1;     // wave row half (0..1) -> 64 rows
    const int wc = wave & 1;      // wave col half

    const int rowBase = ti * BM;
    const int colBase = tj * BM;

    const int lm = lane & 15;           // m/n within 16x16 fragment
    const int lk = (lane >> 4) * 8;     // k elem base within fragment (quad*8)

    // staging lane geometry: 16 chunks of 1KB (8 rows x 8 groups of 16B)
    const int srow = lane >> 3;                 // row within chunk (0..7)
    const int skel = ((lane & 7) ^ srow) * 8;   // swizzled global k offset

    f32x4 acc[4][4] = {};

    for (int k0 = 0; k0 < DIM; k0 += BK) {
        #pragma unroll
        for (int c = 0; c < 4; ++c) {
            const int chunk = wave * 4 + c;          // wave-uniform
            const int r = chunk * 8 + srow;          // 0..127
            const __hip_bfloat16* ga = X + (size_t)(rowBase + r) * DIM + k0 + skel;
            const __hip_bfloat16* gb = Y + (size_t)(colBase + r) * DIM + k0 + skel;
            __builtin_amdgcn_global_load_lds(
                (const __attribute__((address_space(1))) void*)ga,
                (__attribute__((address_space(3))) void*)(As + chunk * 512),
                16, 0, 0);
            __builtin_amdgcn_global_load_lds(
                (const __attribute__((address_space(1))) void*)gb,
                (__attribute__((address_space(3))) void*)(Bs + chunk * 512),
                16, 0, 0);
        }
        __syncthreads();

        #pragma unroll
        for (int kk = 0; kk < BK; kk += 32) {
            const int g = (kk + lk) >> 3;       // k group 0..7 (quad-dependent)
            bf16x8 afr[4], bfr[4];
            #pragma unroll
            for (int f = 0; f < 4; ++f) {
                const int ra = wr * 64 + f * 16 + lm;
                const int rb = wc * 64 + f * 16 + lm;
                afr[f] = *(const bf16x8*)(As + ra * BK + ((g ^ (ra & 7)) << 3));
                bfr[f] = *(const bf16x8*)(Bs + rb * BK + ((g ^ (rb & 7)) << 3));
            }
            #pragma unroll
            for (int fr = 0; fr < 4; ++fr)
                #pragma unroll
                for (int fc = 0; fc < 4; ++fc)
                    acc[fr][fc] = __builtin_amdgcn_mfma_f32_16x16x32_bf16(
                        afr[fr], bfr[fc], acc[fr][fc], 0, 0, 0);
        }
        __syncthreads();
    }

    // ---- epilogue: exp, wave partials -> LDS combine -> coalesced atomics ----
    #pragma unroll
    for (int fr = 0; fr < 4; ++fr)
        #pragma unroll
        for (int fc = 0; fc < 4; ++fc)
            #pragma unroll
            for (int r = 0; r < 4; ++r)
                acc[fr][fc][r] = __expf(acc[fr][fc][r] * TAU_INV);

    const bool do_col = (Scol != nullptr) || (symmetric && ti != tj);
    float* colDst = (Scol != nullptr) ? Scol : Srow;

    // reuse As as fp32 scratch (safe: all waves passed the final barrier)
    float* rowsc = (float*)As;          // [2 (wc)][128]
    float* colsc = rowsc + 256;         // [2 (wr)][128]

    // C/D layout (m89/m91): col = lane&15, row = (lane>>4)*4 + reg
    #pragma unroll
    for (int fr = 0; fr < 4; ++fr) {
        #pragma unroll
        for (int r = 0; r < 4; ++r) {
            float s = acc[fr][0][r] + acc[fr][1][r] + acc[fr][2][r] + acc[fr][3][r];
            s += __shfl_xor(s, 1, 64);
            s += __shfl_xor(s, 2, 64);
            s += __shfl_xor(s, 4, 64);
            s += __shfl_xor(s, 8, 64);
            if ((lane & 15) == 0)
                rowsc[wc * 128 + wr * 64 + fr * 16 + (lane >> 4) * 4 + r] = s;
        }
    }
    if (do_col) {
        #pragma unroll
        for (int fc = 0; fc < 4; ++fc) {
            float s = 0.0f;
            #pragma unroll
            for (int fr = 0; fr < 4; ++fr)
                #pragma unroll
                for (int r = 0; r < 4; ++r)
                    s += acc[fr][fc][r];
            s += __shfl_xor(s, 16, 64);
            s += __shfl_xor(s, 32, 64);
            if (lane < 16)
                colsc[wr * 128 + wc * 64 + fc * 16 + lm] = s;
        }
    }
    __syncthreads();

    if (tid < 128) {
        atomicAdd(&Srow[rowBase + tid], rowsc[tid] + rowsc[128 + tid]);
    } else if (do_col) {
        const int c = tid - 128;
        atomicAdd(&colDst[colBase + c], colsc[c] + colsc[128 + c]);
    }
}

// ---------------------------------------------------------------------------
// Kernel 3: per-row loss + mean reduction.
// ---------------------------------------------------------------------------
__global__ __launch_bounds__(256) void loss_kernel(
    const float* __restrict__ S_aa, const float* __restrict__ S_abr,
    const float* __restrict__ S_abc, const float* __restrict__ S_bb,
    const float* __restrict__ d_aa, const float* __restrict__ d_bb,
    const float* __restrict__ pos, float* __restrict__ out)
{
    const int i = blockIdx.x * 256 + threadIdx.x;
    const float den1 = S_aa[i] + S_abr[i] - expf(TAU_INV * d_aa[i]);
    const float den2 = S_bb[i] + S_abc[i] - expf(TAU_INV * d_bb[i]);
    float v = 0.5f * (logf(den1) + logf(den2)) - TAU_INV * pos[i];

    __shared__ float red[4];
    #pragma unroll
    for (int m = 1; m < 64; m <<= 1) v += __shfl_xor(v, m, 64);
    if ((threadIdx.x & 63) == 0) red[threadIdx.x >> 6] = v;
    __syncthreads();
    if (threadIdx.x == 0)
        atomicAdd(out, (red[0] + red[1] + red[2] + red[3]) * (1.0f / N_ROWS));
}

// ---------------------------------------------------------------------------
extern "C" void kernel_launch(void* const* d_in, const int* in_sizes, int n_in,
                              void* d_out, int out_size, void* d_ws, size_t ws_size,
                              hipStream_t stream)
{
    const float* z1 = (const float*)d_in[0];
    const float* z2 = (const float*)d_in[1];
    float* out = (float*)d_out;

    char* ws = (char*)d_ws;
    __hip_bfloat16* An = (__hip_bfloat16*)ws;                        // 4 MB
    __hip_bfloat16* Bn = (__hip_bfloat16*)(ws + 4194304);            // 4 MB
    float* S_aa  = (float*)(ws + 8388608);
    float* S_abr = S_aa  + N_ROWS;
    float* S_abc = S_abr + N_ROWS;
    float* S_bb  = S_abc + N_ROWS;
    float* d_aa  = S_bb  + N_ROWS;
    float* d_bb  = d_aa  + N_ROWS;
    float* pos   = d_bb  + N_ROWS;

    hipMemsetAsync(S_aa, 0, 4 * N_ROWS * sizeof(float), stream);
    hipMemsetAsync(out, 0, sizeof(float), stream);

    normalize_kernel<<<N_ROWS, 256, 0, stream>>>(z1, z2, An, Bn, d_aa, d_bb, pos);

    dim3 grid(N_ROWS / BM, N_ROWS / BM, 3);   // z: 0=AB, 1=AA, 2=BB
    gram3_kernel<<<grid, 256, 0, stream>>>(An, Bn, S_aa, S_bb, S_abr, S_abc);

    loss_kernel<<<N_ROWS / 256, 256, 0, stream>>>(S_aa, S_abr, S_abc, S_bb,
                                                  d_aa, d_bb, pos, out);
}